// Round 18
// baseline (178.406 us; speedup 1.0000x reference)
//
#include <hip/hip_runtime.h>
#include <hip/hip_bf16.h>
#include <math.h>

#define SEQ   168
#define BATCH 4096
#define NOUT  9
#define NBLK  256        // BATCH / 16

typedef short bf16x8 __attribute__((ext_vector_type(8)));
typedef float f32x4  __attribute__((ext_vector_type(4)));

#define MFMA(a,b,c) __builtin_amdgcn_mfma_f32_16x16x32_bf16((a),(b),(c),0,0,0)

#define L2E  1.44269504088896340736f   // log2(e)
#define CLMP 40.0f                     // exp2-arg upper clamp: products stay finite

static __device__ __forceinline__ float e2(float x){        // raw v_exp_f32
    return __builtin_amdgcn_exp2f(x);
}
static __device__ __forceinline__ float bf2f(unsigned short h){
    unsigned int u = ((unsigned int)h) << 16;
    return __builtin_bit_cast(float, u);
}
static __device__ __forceinline__ unsigned short f2bf(float f){  // HW RNE
    return __builtin_bit_cast(unsigned short, __float2bfloat16(f));
}
// 2-term split kept ONLY for the head weights (4 MFMAs, direct output impact)
static __device__ __forceinline__ void splitf(float f, unsigned short& hi, unsigned short& lo){
    hi = f2bf(f);
    float r = f - bf2f(hi);
    lo = (unsigned short)(__builtin_bit_cast(unsigned int, r) >> 16);
}
static __device__ __forceinline__ bf16x8 ldfrag(const unsigned short* p){
    const uint4 q = *reinterpret_cast<const uint4*>(p);
    return __builtin_bit_cast(bf16x8, q);
}

// LSTM cell update, trans-minimized, native exp2. Preacts PRE-SCALED:
//   pi,pf,po = preact*log2e ; pg = preact*2*log2e.
// 5 exp2 + 2 rcp per cell; exp2(-big)->0 gives exact saturation.
static __device__ __forceinline__ float cellupd(float pi, float pf, float pg,
                                                float po, float& c){
    const float Ai = 1.0f + e2(fminf(-pi, CLMP));
    const float Af = 1.0f + e2(fminf(-pf, CLMP));
    const float Bg = 1.0f + e2(fminf( pg, CLMP));
    const float Ao = 1.0f + e2(fminf(-po, CLMP));
    const float t1 = Ai * Bg;
    const float r  = __builtin_amdgcn_rcpf(Af * t1);
    const float cn = fmaf(c, t1, Af * (Bg - 2.0f)) * r;
    c = cn;
    const float Bc = 1.0f + e2(fminf(cn * (2.0f * L2E), CLMP));
    return (Bc - 2.0f) * __builtin_amdgcn_rcpf(Ao * Bc);
}

// ---- distributed progress-slot sync (no atomic RMW, no central phase) ----
// Each wave owns one LDS slot; posts tick t with a release store after its
// shared-memory writes drain. Rendezvous/guards = min over 4 slots.
// r17 DEADLOCK fix: l1's own-group rendezvous must be skipped at t=1 (slots
// start at -1 and group-1's first post is at END of tick 1 — waiting at the
// top of tick 1 is a self-rendezvous-before-first-post deadlock).
static __device__ __forceinline__ int min4(const int* s){
    int a = __hip_atomic_load(&s[0], __ATOMIC_ACQUIRE, __HIP_MEMORY_SCOPE_WORKGROUP);
    int b = __hip_atomic_load(&s[1], __ATOMIC_ACQUIRE, __HIP_MEMORY_SCOPE_WORKGROUP);
    int c = __hip_atomic_load(&s[2], __ATOMIC_ACQUIRE, __HIP_MEMORY_SCOPE_WORKGROUP);
    int d = __hip_atomic_load(&s[3], __ATOMIC_ACQUIRE, __HIP_MEMORY_SCOPE_WORKGROUP);
    return min(min(a, b), min(c, d));
}
static __device__ __forceinline__ void wait4(const int* s, int need){
    if (min4(s) >= need) return;
    do { __builtin_amdgcn_s_sleep(1); } while (min4(s) < need);
}
static __device__ __forceinline__ void post(int* slot, int t, int lane){
    asm volatile("s_waitcnt lgkmcnt(0)" ::: "memory");   // own ds writes done
    if (lane == 0)
        __hip_atomic_store(slot, t, __ATOMIC_RELEASE, __HIP_MEMORY_SCOPE_WORKGROUP);
}

// r16 schedule/work order, sync = distributed slots.
//   Group 0 (waves 0-3): layer0 tick t in [0,SEQ): h0_t -> sH0[t%3].
//   Group 1 (waves 4-7): layer1 tick t in [1,SEQ]: step t-1 + head for step t-2
//     (rotating wave, reuses live A1H frags); epilogue emits step SEQ-1.
// Guards: l0 top-of-tick (t>=1) waits own >= t-1; overwrite waits l1 >= t-2.
//         l1 top-of-tick (t>=2) waits own >= t-1; h0-read waits l0 >= t-1.
// Intra-group skew < 1 tick bounds every LDS buffer reuse.
__global__ __launch_bounds__(512, 2)
void lstm_fused(const float* __restrict__ x,
                const float* __restrict__ Wih0, const float* __restrict__ Whh0,
                const float* __restrict__ bih0, const float* __restrict__ bhh0,
                const float* __restrict__ Wih1, const float* __restrict__ Whh1,
                const float* __restrict__ bih1, const float* __restrict__ bhh1,
                const float* __restrict__ Wout, const float* __restrict__ bout,
                float* __restrict__ out)
{
    __shared__ __align__(16) unsigned short sXH[2][16][72];   // x hi, stride 144B
    __shared__ __align__(16) unsigned short sH0H[3][16][72];  // h0 hi, triple buf
    __shared__ __align__(16) unsigned short sH1H[2][16][72];  // h1 hi
    __shared__ int sync[8];   // [0..3] = group0 wave slots, [4..7] = group1

    const int tid  = threadIdx.x;
    const int half = tid >> 8;
    const int w2   = (tid >> 6) & 3;
    const int l    = tid & 63;
    const int lr   = l & 15;
    const int g    = l >> 4;
    const int r0   = blockIdx.x * 16;
    const int cg   = w2 * 16 + lr;

    // per-gate weight/bias pre-scale: i,f,o by log2e; g by 2*log2e
    const float WS[4] = { L2E, L2E, 2.0f * L2E, L2E };

    if (tid < 8) sync[tid] = -1;

    for (int i = tid; i < (int)(2*16*72/2); i += 512){
        ((unsigned int*)sXH)[i]  = 0u;
        ((unsigned int*)sH1H)[i] = 0u;
    }
    for (int i = tid; i < (int)(3*16*72/2); i += 512)
        ((unsigned int*)sH0H)[i] = 0u;
    __syncthreads();
    // stage x_0 into buffer 0
    if (tid < 96){
        const float4 v = *reinterpret_cast<const float4*>(&x[(size_t)r0 * 24 + tid * 4]);
        const int row = (tid * 4) / 24, col = (tid * 4) % 24;
        ushort4 w = { f2bf(v.x), f2bf(v.y), f2bf(v.z), f2bf(v.w) };
        *reinterpret_cast<ushort4*>(&sXH[0][row][col]) = w;
    }
    __syncthreads();

    if (half == 0){
        // ================= LAYER 0 waves (group 0) =================
        bf16x8 B0H[4][3];   // ks0 = Wih0 (K=24 pad 32), ks1,2 = Whh0; scaled bf16
        #pragma unroll
        for (int gt = 0; gt < 4; ++gt){
            const int c = gt * 64 + cg;
            const float sc = WS[gt];
            bf16x8 bh = {0,0,0,0,0,0,0,0};
            if (g < 3){
                const float* pw = &Wih0[c * 24 + g * 8];
                #pragma unroll
                for (int j = 0; j < 8; ++j) bh[j] = (short)f2bf(pw[j] * sc);
            }
            B0H[gt][0] = bh;
            #pragma unroll
            for (int ks = 0; ks < 2; ++ks){
                bf16x8 ch;
                const float* pw = &Whh0[c * 64 + ks * 32 + g * 8];
                #pragma unroll
                for (int j = 0; j < 8; ++j) ch[j] = (short)f2bf(pw[j] * sc);
                B0H[gt][1+ks] = ch;
            }
        }
        float b0[4];
        #pragma unroll
        for (int gt = 0; gt < 4; ++gt) b0[gt] = (bih0[gt*64 + cg] + bhh0[gt*64 + cg]) * WS[gt];

        const float* xfp = x + ((size_t)BATCH + r0) * 24 + tid * 4;  // x for tick t+1
        float c0[4] = {0,0,0,0};
        int pw = 0, pr = 2;   // pw = t%3 (write h0_t), pr = (t-1)%3 (read h0_{t-1})
        for (int t = 0; t < SEQ; ++t){
            // own-group rendezvous for tick t-1 data (h0[pr], sXH[px] complete)
            if (t >= 1) wait4(&sync[0], t - 1);
            const int px = t & 1;
            const bool ldx = (tid < 96) && (t + 1 < SEQ);
            float4 pref;
            if (ldx){ pref = *reinterpret_cast<const float4*>(xfp); xfp += (size_t)BATCH * 24; }

            const bf16x8 AxH = ldfrag(&sXH[px][lr][g*8]);
            bf16x8 A0H[2];
            #pragma unroll
            for (int ks = 0; ks < 2; ++ks)
                A0H[ks] = ldfrag(&sH0H[pr][lr][ks*32 + g*8]);

            f32x4 a0[4];
            #pragma unroll
            for (int gt = 0; gt < 4; ++gt){ f32x4 a = {b0[gt],b0[gt],b0[gt],b0[gt]}; a0[gt] = a; }
            #pragma unroll
            for (int gt = 0; gt < 4; ++gt) a0[gt] = MFMA(AxH, B0H[gt][0], a0[gt]);
            #pragma unroll
            for (int ks = 0; ks < 2; ++ks){
                #pragma unroll
                for (int gt = 0; gt < 4; ++gt) a0[gt] = MFMA(A0H[ks], B0H[gt][1+ks], a0[gt]);
            }
            unsigned short hh[4];
            #pragma unroll
            for (int i = 0; i < 4; ++i)
                hh[i] = f2bf(cellupd(a0[0][i], a0[1][i], a0[2][i], a0[3][i], c0[i]));
            // x-stage write (group-private; safe once own group >= t-1)
            if (ldx){
                const int row = (tid * 4) / 24, col = (tid * 4) % 24;
                ushort4 w = { f2bf(pref.x), f2bf(pref.y), f2bf(pref.z), f2bf(pref.w) };
                *reinterpret_cast<ushort4*>(&sXH[px ^ 1][row][col]) = w;
            }
            // overwrite guard: buffer pw holds h0_{t-3}, consumed by l1 at tick t-2
            if (t >= 3) wait4(&sync[4], t - 2);
            #pragma unroll
            for (int i = 0; i < 4; ++i)
                sH0H[pw][g * 4 + i][cg] = hh[i];
            post(&sync[w2], t, l);
            pr = pw;
            pw = (pw == 2) ? 0 : pw + 1;
        }
    } else {
        // ================= LAYER 1 + head waves (group 1) =================
        bf16x8 B1H[4][4];   // ks0,1 = Wih1 (h0 in), ks2,3 = Whh1 (h1 fb); scaled
        #pragma unroll
        for (int gt = 0; gt < 4; ++gt){
            const int c = gt * 64 + cg;
            const float sc = WS[gt];
            #pragma unroll
            for (int ks = 0; ks < 2; ++ks){
                bf16x8 ch;
                const float* pw = &Wih1[c * 64 + ks * 32 + g * 8];
                #pragma unroll
                for (int j = 0; j < 8; ++j) ch[j] = (short)f2bf(pw[j] * sc);
                B1H[gt][ks] = ch;
            }
            #pragma unroll
            for (int ks = 0; ks < 2; ++ks){
                bf16x8 ch;
                const float* pw = &Whh1[c * 64 + ks * 32 + g * 8];
                #pragma unroll
                for (int j = 0; j < 8; ++j) ch[j] = (short)f2bf(pw[j] * sc);
                B1H[gt][2+ks] = ch;
            }
        }
        float b1[4];
        #pragma unroll
        for (int gt = 0; gt < 4; ++gt) b1[gt] = (bih1[gt*64 + cg] + bhh1[gt*64 + cg]) * WS[gt];

        // head weights: keep hi+lo, UNSCALED (no nonlinearity downstream)
        const int oc = lr;
        bf16x8 WoH[2], WoL[2];
        #pragma unroll
        for (int tt = 0; tt < 2; ++tt){
            bf16x8 bh = {0,0,0,0,0,0,0,0}, bl = {0,0,0,0,0,0,0,0};
            if (oc < NOUT){
                const float* pw = &Wout[oc * 64 + tt * 32 + g * 8];
                #pragma unroll
                for (int j = 0; j < 8; ++j){ unsigned short hh, ll; splitf(pw[j], hh, ll); bh[j]=(short)hh; bl[j]=(short)ll; }
            }
            WoH[tt] = bh; WoL[tt] = bl;
        }
        const float bo0 = (oc < NOUT) ? bout[oc] : 0.f;
        float* houtp = out + (size_t)(r0 + g * 4) * NOUT + oc;

        float c1[4] = {0,0,0,0};
        int pr0 = 0;   // (t-1) % 3, starting at t=1
        for (int t = 1; t <= SEQ; ++t){
            // own-group rendezvous for tick t-1 (h1 buffer reuse safe).
            // t=1 has no prior own-group tick: slots are -1 and first post is
            // at the END of this tick -> waiting here would deadlock (r17 bug).
            if (t >= 2) wait4(&sync[4], t - 1);
            const int p = t & 1;
            // own-group feedback frags (= h1_{t-2}, also the head's input)
            bf16x8 A1H[2];
            #pragma unroll
            for (int ks = 0; ks < 2; ++ks)
                A1H[ks] = ldfrag(&sH1H[p][lr][ks*32 + g*8]);
            // h0_{t-1} ready? (l0 runs ahead -> almost always satisfied)
            wait4(&sync[0], t - 1);
            bf16x8 A0H[2];
            #pragma unroll
            for (int ks = 0; ks < 2; ++ks)
                A0H[ks] = ldfrag(&sH0H[pr0][lr][ks*32 + g*8]);

            f32x4 a1[4];
            #pragma unroll
            for (int gt = 0; gt < 4; ++gt){ f32x4 a = {b1[gt],b1[gt],b1[gt],b1[gt]}; a1[gt] = a; }
            // feedback MFMAs first (A0 read latency hides underneath)
            #pragma unroll
            for (int ks = 0; ks < 2; ++ks){
                #pragma unroll
                for (int gt = 0; gt < 4; ++gt) a1[gt] = MFMA(A1H[ks], B1H[gt][2+ks], a1[gt]);
            }
            // head for step t-2: rotating wave, reuses A1H (no LDS reads, no waits)
            if (t >= 2 && w2 == (t & 3)){
                f32x4 ha = {bo0, bo0, bo0, bo0};
                ha = MFMA(A1H[0], WoH[0], ha);
                ha = MFMA(A1H[0], WoL[0], ha);
                ha = MFMA(A1H[1], WoH[1], ha);
                ha = MFMA(A1H[1], WoL[1], ha);
                if (oc < NOUT){
                    #pragma unroll
                    for (int i = 0; i < 4; ++i)
                        houtp[(size_t)i * NOUT] = ha[i];
                }
            }
            if (t >= 2) houtp += (size_t)BATCH * NOUT;
            // input-side MFMAs
            #pragma unroll
            for (int ks = 0; ks < 2; ++ks){
                #pragma unroll
                for (int gt = 0; gt < 4; ++gt) a1[gt] = MFMA(A0H[ks], B1H[gt][ks], a1[gt]);
            }
            #pragma unroll
            for (int i = 0; i < 4; ++i)
                sH1H[p ^ 1][g * 4 + i][cg] =
                    f2bf(cellupd(a1[0][i], a1[1][i], a1[2][i], a1[3][i], c1[i]));
            post(&sync[4 + w2], t, l);
            pr0 = (pr0 == 2) ? 0 : pr0 + 1;
        }
        // epilogue: head for step SEQ-1 (h1_{SEQ-1} in sH1[(SEQ+1)&1])
        {
            wait4(&sync[4], SEQ);   // all group-1 writes of tick SEQ landed
            const int pe = (SEQ + 1) & 1;
            if (w2 == ((SEQ + 1) & 3)){
                bf16x8 A1H0 = ldfrag(&sH1H[pe][lr][g*8]);
                bf16x8 A1H1 = ldfrag(&sH1H[pe][lr][32 + g*8]);
                f32x4 ha = {bo0, bo0, bo0, bo0};
                ha = MFMA(A1H0, WoH[0], ha);
                ha = MFMA(A1H0, WoL[0], ha);
                ha = MFMA(A1H1, WoH[1], ha);
                ha = MFMA(A1H1, WoL[1], ha);
                if (oc < NOUT){
                    #pragma unroll
                    for (int i = 0; i < 4; ++i)
                        houtp[(size_t)i * NOUT] = ha[i];
                }
            }
        }
    }
}

extern "C" void kernel_launch(void* const* d_in, const int* in_sizes, int n_in,
                              void* d_out, int out_size, void* d_ws, size_t ws_size,
                              hipStream_t stream)
{
    const float* x    = (const float*)d_in[0];
    const float* Wih0 = (const float*)d_in[1];
    const float* Whh0 = (const float*)d_in[2];
    const float* bih0 = (const float*)d_in[3];
    const float* bhh0 = (const float*)d_in[4];
    const float* Wih1 = (const float*)d_in[5];
    const float* Whh1 = (const float*)d_in[6];
    const float* bih1 = (const float*)d_in[7];
    const float* bhh1 = (const float*)d_in[8];
    const float* Wout = (const float*)d_in[9];
    const float* bout = (const float*)d_in[10];
    float* out = (float*)d_out;

    lstm_fused<<<NBLK, 512, 0, stream>>>(x, Wih0, Whh0, bih0, bhh0,
                                         Wih1, Whh1, bih1, bhh1,
                                         Wout, bout, out);
}

// Round 19
// 177.089 us; speedup vs baseline: 1.0074x; 1.0074x over previous
//
#include <hip/hip_runtime.h>
#include <hip/hip_bf16.h>
#include <math.h>

#define SEQ   168
#define BATCH 4096
#define NOUT  9
#define NBLK  256        // BATCH / 16

typedef short bf16x8 __attribute__((ext_vector_type(8)));
typedef float f32x4  __attribute__((ext_vector_type(4)));

#define MFMA(a,b,c) __builtin_amdgcn_mfma_f32_16x16x32_bf16((a),(b),(c),0,0,0)

#define L2E  1.44269504088896340736f   // log2(e)
#define CLMP 40.0f                     // exp2-arg upper clamp

static __device__ __forceinline__ float e2(float x){        // raw v_exp_f32
    return __builtin_amdgcn_exp2f(x);
}
static __device__ __forceinline__ float bf2f(unsigned short h){
    unsigned int u = ((unsigned int)h) << 16;
    return __builtin_bit_cast(float, u);
}
static __device__ __forceinline__ unsigned short f2bf(float f){  // HW RNE
    return __builtin_bit_cast(unsigned short, __float2bfloat16(f));
}
// 2-term split kept ONLY for the head weights
static __device__ __forceinline__ void splitf(float f, unsigned short& hi, unsigned short& lo){
    hi = f2bf(f);
    float r = f - bf2f(hi);
    lo = (unsigned short)(__builtin_bit_cast(unsigned int, r) >> 16);
}
static __device__ __forceinline__ bf16x8 ldfrag(const unsigned short* p){
    const uint4 q = *reinterpret_cast<const uint4*>(p);
    return __builtin_bit_cast(bf16x8, q);
}

// Combine phase of the cell update, given per-gate exp2 results E[gt][row]:
//   Ai=1+E0, Af=1+E1, Bg=1+E2, Ao=1+E3  (preacts pre-scaled by log2e / 2log2e;
//   E computed gate-major right after each gate's MFMAs -> exp latency hides
//   under the remaining gates' MFMAs).
static __device__ __forceinline__ float cellcomb(float E0, float E1, float E2,
                                                 float E3, float& c){
    const float Ai = 1.0f + E0;
    const float Af = 1.0f + E1;
    const float Bg = 1.0f + E2;
    const float Ao = 1.0f + E3;
    const float t1 = Ai * Bg;
    const float r  = __builtin_amdgcn_rcpf(Af * t1);
    const float cn = fmaf(c, t1, Af * (Bg - 2.0f)) * r;
    c = cn;
    const float Bc = 1.0f + e2(fminf(cn * (2.0f * L2E), CLMP));
    return (Bc - 2.0f) * __builtin_amdgcn_rcpf(Ao * Bc);
}

// group-local sense-reversing barrier over 4 waves (proven r16 form)
static __device__ __forceinline__ void gbar(int* cnt, int* phs, int* done,
                                            int tickval, int& ph, int lane){
    asm volatile("s_waitcnt lgkmcnt(0)" ::: "memory");
    if (lane == 0){
        int old = __hip_atomic_fetch_add(cnt, 1, __ATOMIC_ACQ_REL,
                                         __HIP_MEMORY_SCOPE_WORKGROUP);
        if (old == 3){
            *cnt = 0;
            __hip_atomic_store(done, tickval, __ATOMIC_RELEASE,
                               __HIP_MEMORY_SCOPE_WORKGROUP);
            __hip_atomic_store(phs, ph ^ 1, __ATOMIC_RELEASE,
                               __HIP_MEMORY_SCOPE_WORKGROUP);
        }
    }
    while (__hip_atomic_load(phs, __ATOMIC_ACQUIRE,
                             __HIP_MEMORY_SCOPE_WORKGROUP) == ph)
        __builtin_amdgcn_s_sleep(1);
    ph ^= 1;
}
static __device__ __forceinline__ void wait_ge(int* done, int need){
    if (__hip_atomic_load(done, __ATOMIC_ACQUIRE, __HIP_MEMORY_SCOPE_WORKGROUP) >= need) return;
    do { __builtin_amdgcn_s_sleep(1); }
    while (__hip_atomic_load(done, __ATOMIC_ACQUIRE, __HIP_MEMORY_SCOPE_WORKGROUP) < need);
}

// r16 schedule + (1) h0 quad-buffer (overwrite guard t-3: +1 tick jitter slack),
// (2) gate-major MFMA order with early per-gate exps, (3) x-stage before wait.
//   Group 0 (waves 0-3): layer0 tick t in [0,SEQ): h0_t -> sH0[t%4].
//   Group 1 (waves 4-7): layer1 tick t in [1,SEQ]: step t-1 + head for step t-2
//     (rotating wave, reuses live A1H frags); epilogue emits step SEQ-1.
__global__ __launch_bounds__(512, 2)
void lstm_fused(const float* __restrict__ x,
                const float* __restrict__ Wih0, const float* __restrict__ Whh0,
                const float* __restrict__ bih0, const float* __restrict__ bhh0,
                const float* __restrict__ Wih1, const float* __restrict__ Whh1,
                const float* __restrict__ bih1, const float* __restrict__ bhh1,
                const float* __restrict__ Wout, const float* __restrict__ bout,
                float* __restrict__ out)
{
    __shared__ __align__(16) unsigned short sXH[2][16][72];   // x hi, stride 144B
    __shared__ __align__(16) unsigned short sH0H[4][16][72];  // h0 hi, quad buf
    __shared__ __align__(16) unsigned short sH1H[2][16][72];  // h1 hi
    __shared__ int sync[8];  // [0,1]=cnt, [2,3]=phase, [4]=l0_done, [5]=l1_done

    const int tid  = threadIdx.x;
    const int half = tid >> 8;
    const int w2   = (tid >> 6) & 3;
    const int l    = tid & 63;
    const int lr   = l & 15;
    const int g    = l >> 4;
    const int r0   = blockIdx.x * 16;
    const int cg   = w2 * 16 + lr;

    // per-gate weight/bias pre-scale: i,f,o by log2e; g by 2*log2e
    const float WS[4] = { L2E, L2E, 2.0f * L2E, L2E };

    if (tid < 8) sync[tid] = (tid == 4) ? -1 : 0;

    for (int i = tid; i < (int)(2*16*72/2); i += 512){
        ((unsigned int*)sXH)[i]  = 0u;
        ((unsigned int*)sH1H)[i] = 0u;
    }
    for (int i = tid; i < (int)(4*16*72/2); i += 512)
        ((unsigned int*)sH0H)[i] = 0u;
    __syncthreads();
    // stage x_0 into buffer 0
    if (tid < 96){
        const float4 v = *reinterpret_cast<const float4*>(&x[(size_t)r0 * 24 + tid * 4]);
        const int row = (tid * 4) / 24, col = (tid * 4) % 24;
        ushort4 w = { f2bf(v.x), f2bf(v.y), f2bf(v.z), f2bf(v.w) };
        *reinterpret_cast<ushort4*>(&sXH[0][row][col]) = w;
    }
    __syncthreads();

    if (half == 0){
        // ================= LAYER 0 waves (group 0) =================
        bf16x8 B0H[4][3];   // ks0 = Wih0 (K=24 pad 32), ks1,2 = Whh0; scaled bf16
        #pragma unroll
        for (int gt = 0; gt < 4; ++gt){
            const int c = gt * 64 + cg;
            const float sc = WS[gt];
            bf16x8 bh = {0,0,0,0,0,0,0,0};
            if (g < 3){
                const float* pw = &Wih0[c * 24 + g * 8];
                #pragma unroll
                for (int j = 0; j < 8; ++j) bh[j] = (short)f2bf(pw[j] * sc);
            }
            B0H[gt][0] = bh;
            #pragma unroll
            for (int ks = 0; ks < 2; ++ks){
                bf16x8 ch;
                const float* pw = &Whh0[c * 64 + ks * 32 + g * 8];
                #pragma unroll
                for (int j = 0; j < 8; ++j) ch[j] = (short)f2bf(pw[j] * sc);
                B0H[gt][1+ks] = ch;
            }
        }
        float b0[4];
        #pragma unroll
        for (int gt = 0; gt < 4; ++gt) b0[gt] = (bih0[gt*64 + cg] + bhh0[gt*64 + cg]) * WS[gt];

        const float* xfp = x + ((size_t)BATCH + r0) * 24 + tid * 4;  // x for tick t+1
        float c0[4] = {0,0,0,0};
        int ph = 0;
        int pw = 0, pr = 3;   // pw = t%4 (write h0_t), pr = (t-1)%4 (read h0_{t-1})
        for (int t = 0; t < SEQ; ++t){
            const int px = t & 1;
            const bool ldx = (tid < 96) && (t + 1 < SEQ);
            float4 pref;
            if (ldx){ pref = *reinterpret_cast<const float4*>(xfp); xfp += (size_t)BATCH * 24; }

            const bf16x8 AxH = ldfrag(&sXH[px][lr][g*8]);
            bf16x8 A0H[2];
            #pragma unroll
            for (int ks = 0; ks < 2; ++ks)
                A0H[ks] = ldfrag(&sH0H[pr][lr][ks*32 + g*8]);

            // gate-major MFMAs + early per-gate exps (exp hides under next gate)
            float Ex[4][4];
            #pragma unroll
            for (int gt = 0; gt < 4; ++gt){
                f32x4 a = {b0[gt], b0[gt], b0[gt], b0[gt]};
                a = MFMA(AxH,    B0H[gt][0], a);
                a = MFMA(A0H[0], B0H[gt][1], a);
                a = MFMA(A0H[1], B0H[gt][2], a);
                const float sg = (gt == 2) ? 1.0f : -1.0f;
                #pragma unroll
                for (int i = 0; i < 4; ++i)
                    Ex[gt][i] = e2(fminf(sg * a[i], CLMP));
            }
            unsigned short hh[4];
            #pragma unroll
            for (int i = 0; i < 4; ++i)
                hh[i] = f2bf(cellcomb(Ex[0][i], Ex[1][i], Ex[2][i], Ex[3][i], c0[i]));
            // x-stage write first (group-private, no cross-group ordering)
            if (ldx){
                const int row = (tid * 4) / 24, col = (tid * 4) % 24;
                ushort4 w = { f2bf(pref.x), f2bf(pref.y), f2bf(pref.z), f2bf(pref.w) };
                *reinterpret_cast<ushort4*>(&sXH[px ^ 1][row][col]) = w;
            }
            // overwrite guard: buffer pw holds h0_{t-4}, consumed by l1 at tick t-3
            if (t >= 4) wait_ge(&sync[5], t - 3);
            #pragma unroll
            for (int i = 0; i < 4; ++i)
                sH0H[pw][g * 4 + i][cg] = hh[i];
            gbar(&sync[0], &sync[2], &sync[4], t, ph, l);
            pr = pw;
            pw = (pw + 1) & 3;
        }
    } else {
        // ================= LAYER 1 + head waves (group 1) =================
        bf16x8 B1H[4][4];   // ks0,1 = Wih1 (h0 in), ks2,3 = Whh1 (h1 fb); scaled
        #pragma unroll
        for (int gt = 0; gt < 4; ++gt){
            const int c = gt * 64 + cg;
            const float sc = WS[gt];
            #pragma unroll
            for (int ks = 0; ks < 2; ++ks){
                bf16x8 ch;
                const float* pw = &Wih1[c * 64 + ks * 32 + g * 8];
                #pragma unroll
                for (int j = 0; j < 8; ++j) ch[j] = (short)f2bf(pw[j] * sc);
                B1H[gt][ks] = ch;
            }
            #pragma unroll
            for (int ks = 0; ks < 2; ++ks){
                bf16x8 ch;
                const float* pw = &Whh1[c * 64 + ks * 32 + g * 8];
                #pragma unroll
                for (int j = 0; j < 8; ++j) ch[j] = (short)f2bf(pw[j] * sc);
                B1H[gt][2+ks] = ch;
            }
        }
        float b1[4];
        #pragma unroll
        for (int gt = 0; gt < 4; ++gt) b1[gt] = (bih1[gt*64 + cg] + bhh1[gt*64 + cg]) * WS[gt];

        // head weights: keep hi+lo, UNSCALED
        const int oc = lr;
        bf16x8 WoH[2], WoL[2];
        #pragma unroll
        for (int tt = 0; tt < 2; ++tt){
            bf16x8 bh = {0,0,0,0,0,0,0,0}, bl = {0,0,0,0,0,0,0,0};
            if (oc < NOUT){
                const float* pw = &Wout[oc * 64 + tt * 32 + g * 8];
                #pragma unroll
                for (int j = 0; j < 8; ++j){ unsigned short hh, ll; splitf(pw[j], hh, ll); bh[j]=(short)hh; bl[j]=(short)ll; }
            }
            WoH[tt] = bh; WoL[tt] = bl;
        }
        const float bo0 = (oc < NOUT) ? bout[oc] : 0.f;
        float* houtp = out + (size_t)(r0 + g * 4) * NOUT + oc;

        float c1[4] = {0,0,0,0};
        int ph = 0;
        int pr0 = 0;   // (t-1) % 4, starting at t=1
        for (int t = 1; t <= SEQ; ++t){
            const int p = t & 1;
            // own-group feedback frags (= h1_{t-2}, also the head's input)
            bf16x8 A1H[2];
            #pragma unroll
            for (int ks = 0; ks < 2; ++ks)
                A1H[ks] = ldfrag(&sH1H[p][lr][ks*32 + g*8]);
            // h0_{t-1} ready? (l0 runs ahead -> almost always satisfied)
            wait_ge(&sync[4], t - 1);
            bf16x8 A0H[2];
            #pragma unroll
            for (int ks = 0; ks < 2; ++ks)
                A0H[ks] = ldfrag(&sH0H[pr0][lr][ks*32 + g*8]);

            // gate-major MFMAs + early per-gate exps
            float Ex[4][4];
            #pragma unroll
            for (int gt = 0; gt < 4; ++gt){
                f32x4 a = {b1[gt], b1[gt], b1[gt], b1[gt]};
                a = MFMA(A1H[0], B1H[gt][2], a);
                a = MFMA(A1H[1], B1H[gt][3], a);
                a = MFMA(A0H[0], B1H[gt][0], a);
                a = MFMA(A0H[1], B1H[gt][1], a);
                const float sg = (gt == 2) ? 1.0f : -1.0f;
                #pragma unroll
                for (int i = 0; i < 4; ++i)
                    Ex[gt][i] = e2(fminf(sg * a[i], CLMP));
            }
            // head for step t-2: rotating wave, reuses A1H (no LDS reads/waits);
            // overlaps the exp tail of the gate loop
            if (t >= 2 && w2 == (t & 3)){
                f32x4 ha = {bo0, bo0, bo0, bo0};
                ha = MFMA(A1H[0], WoH[0], ha);
                ha = MFMA(A1H[0], WoL[0], ha);
                ha = MFMA(A1H[1], WoH[1], ha);
                ha = MFMA(A1H[1], WoL[1], ha);
                if (oc < NOUT){
                    #pragma unroll
                    for (int i = 0; i < 4; ++i)
                        houtp[(size_t)i * NOUT] = ha[i];
                }
            }
            if (t >= 2) houtp += (size_t)BATCH * NOUT;
            unsigned short hh1[4];
            #pragma unroll
            for (int i = 0; i < 4; ++i)
                hh1[i] = f2bf(cellcomb(Ex[0][i], Ex[1][i], Ex[2][i], Ex[3][i], c1[i]));
            #pragma unroll
            for (int i = 0; i < 4; ++i)
                sH1H[p ^ 1][g * 4 + i][cg] = hh1[i];
            gbar(&sync[1], &sync[3], &sync[5], t, ph, l);
            pr0 = (pr0 + 1) & 3;
        }
        // epilogue: head for step SEQ-1 (h1_{SEQ-1} in sH1[(SEQ+1)&1], stable)
        {
            const int pe = (SEQ + 1) & 1;
            if (w2 == ((SEQ + 1) & 3)){
                bf16x8 A1H0 = ldfrag(&sH1H[pe][lr][g*8]);
                bf16x8 A1H1 = ldfrag(&sH1H[pe][lr][32 + g*8]);
                f32x4 ha = {bo0, bo0, bo0, bo0};
                ha = MFMA(A1H0, WoH[0], ha);
                ha = MFMA(A1H0, WoL[0], ha);
                ha = MFMA(A1H1, WoH[1], ha);
                ha = MFMA(A1H1, WoL[1], ha);
                if (oc < NOUT){
                    #pragma unroll
                    for (int i = 0; i < 4; ++i)
                        houtp[(size_t)i * NOUT] = ha[i];
                }
            }
        }
    }
}

extern "C" void kernel_launch(void* const* d_in, const int* in_sizes, int n_in,
                              void* d_out, int out_size, void* d_ws, size_t ws_size,
                              hipStream_t stream)
{
    const float* x    = (const float*)d_in[0];
    const float* Wih0 = (const float*)d_in[1];
    const float* Whh0 = (const float*)d_in[2];
    const float* bih0 = (const float*)d_in[3];
    const float* bhh0 = (const float*)d_in[4];
    const float* Wih1 = (const float*)d_in[5];
    const float* Whh1 = (const float*)d_in[6];
    const float* bih1 = (const float*)d_in[7];
    const float* bhh1 = (const float*)d_in[8];
    const float* Wout = (const float*)d_in[9];
    const float* bout = (const float*)d_in[10];
    float* out = (float*)d_out;

    lstm_fused<<<NBLK, 512, 0, stream>>>(x, Wih0, Whh0, bih0, bhh0,
                                         Wih1, Whh1, bih1, bhh1,
                                         Wout, bout, out);
}

// Round 20
// 175.749 us; speedup vs baseline: 1.0151x; 1.0076x over previous
//
#include <hip/hip_runtime.h>
#include <hip/hip_bf16.h>
#include <math.h>

#define SEQ   168
#define BATCH 4096
#define NOUT  9
#define NBLK  256        // BATCH / 16

typedef short bf16x8 __attribute__((ext_vector_type(8)));
typedef float f32x4  __attribute__((ext_vector_type(4)));

#define MFMA(a,b,c) __builtin_amdgcn_mfma_f32_16x16x32_bf16((a),(b),(c),0,0,0)

#define L2E  1.44269504088896340736f   // log2(e)
#define CLMP 40.0f                     // exp2-arg upper clamp

static __device__ __forceinline__ float e2(float x){        // raw v_exp_f32
    return __builtin_amdgcn_exp2f(x);
}
static __device__ __forceinline__ float bf2f(unsigned short h){
    unsigned int u = ((unsigned int)h) << 16;
    return __builtin_bit_cast(float, u);
}
static __device__ __forceinline__ unsigned short f2bf(float f){  // HW RNE
    return __builtin_bit_cast(unsigned short, __float2bfloat16(f));
}
// 2-term split kept ONLY for the head weights
static __device__ __forceinline__ void splitf(float f, unsigned short& hi, unsigned short& lo){
    hi = f2bf(f);
    float r = f - bf2f(hi);
    lo = (unsigned short)(__builtin_bit_cast(unsigned int, r) >> 16);
}
static __device__ __forceinline__ bf16x8 ldfrag(const unsigned short* p){
    const uint4 q = *reinterpret_cast<const uint4*>(p);
    return __builtin_bit_cast(bf16x8, q);
}

// LSTM cell update, trans-minimized, native exp2. Preacts PRE-SCALED:
//   pi,pf,po = preact*log2e ; pg = preact*2*log2e.
// 5 exp2 + 2 rcp per cell; exp2(-big)->0 gives exact saturation.
static __device__ __forceinline__ float cellupd(float pi, float pf, float pg,
                                                float po, float& c){
    const float Ai = 1.0f + e2(fminf(-pi, CLMP));
    const float Af = 1.0f + e2(fminf(-pf, CLMP));
    const float Bg = 1.0f + e2(fminf( pg, CLMP));
    const float Ao = 1.0f + e2(fminf(-po, CLMP));
    const float t1 = Ai * Bg;
    const float r  = __builtin_amdgcn_rcpf(Af * t1);
    const float cn = fmaf(c, t1, Af * (Bg - 2.0f)) * r;
    c = cn;
    const float Bc = 1.0f + e2(fminf(cn * (2.0f * L2E), CLMP));
    return (Bc - 2.0f) * __builtin_amdgcn_rcpf(Ao * Bc);
}

// group-local sense-reversing barrier over 4 waves (proven r16 form)
static __device__ __forceinline__ void gbar(int* cnt, int* phs, int* done,
                                            int tickval, int& ph, int lane){
    asm volatile("s_waitcnt lgkmcnt(0)" ::: "memory");
    if (lane == 0){
        int old = __hip_atomic_fetch_add(cnt, 1, __ATOMIC_ACQ_REL,
                                         __HIP_MEMORY_SCOPE_WORKGROUP);
        if (old == 3){
            *cnt = 0;
            __hip_atomic_store(done, tickval, __ATOMIC_RELEASE,
                               __HIP_MEMORY_SCOPE_WORKGROUP);
            __hip_atomic_store(phs, ph ^ 1, __ATOMIC_RELEASE,
                               __HIP_MEMORY_SCOPE_WORKGROUP);
        }
    }
    while (__hip_atomic_load(phs, __ATOMIC_ACQUIRE,
                             __HIP_MEMORY_SCOPE_WORKGROUP) == ph)
        __builtin_amdgcn_s_sleep(1);
    ph ^= 1;
}
static __device__ __forceinline__ void wait_ge(int* done, int need){
    if (__hip_atomic_load(done, __ATOMIC_ACQUIRE, __HIP_MEMORY_SCOPE_WORKGROUP) >= need) return;
    do { __builtin_amdgcn_s_sleep(1); }
    while (__hip_atomic_load(done, __ATOMIC_ACQUIRE, __HIP_MEMORY_SCOPE_WORKGROUP) < need);
}

// r16 schedule (ks-major MFMAs, proven) + h0 quad-buffer (guard t-3) +
// x-stage write hoisted before the cross-group wait.
//   Group 0 (waves 0-3): layer0 tick t in [0,SEQ): h0_t -> sH0[t%4].
//   Group 1 (waves 4-7): layer1 tick t in [1,SEQ]: step t-1 + head for step t-2
//     (rotating wave, reuses live A1H frags); epilogue emits step SEQ-1.
__global__ __launch_bounds__(512, 2)
void lstm_fused(const float* __restrict__ x,
                const float* __restrict__ Wih0, const float* __restrict__ Whh0,
                const float* __restrict__ bih0, const float* __restrict__ bhh0,
                const float* __restrict__ Wih1, const float* __restrict__ Whh1,
                const float* __restrict__ bih1, const float* __restrict__ bhh1,
                const float* __restrict__ Wout, const float* __restrict__ bout,
                float* __restrict__ out)
{
    __shared__ __align__(16) unsigned short sXH[2][16][72];   // x hi, stride 144B
    __shared__ __align__(16) unsigned short sH0H[4][16][72];  // h0 hi, quad buf
    __shared__ __align__(16) unsigned short sH1H[2][16][72];  // h1 hi
    __shared__ int sync[8];  // [0,1]=cnt, [2,3]=phase, [4]=l0_done, [5]=l1_done

    const int tid  = threadIdx.x;
    const int half = tid >> 8;
    const int w2   = (tid >> 6) & 3;
    const int l    = tid & 63;
    const int lr   = l & 15;
    const int g    = l >> 4;
    const int r0   = blockIdx.x * 16;
    const int cg   = w2 * 16 + lr;

    // per-gate weight/bias pre-scale: i,f,o by log2e; g by 2*log2e
    const float WS[4] = { L2E, L2E, 2.0f * L2E, L2E };

    if (tid < 8) sync[tid] = (tid == 4) ? -1 : 0;

    for (int i = tid; i < (int)(2*16*72/2); i += 512){
        ((unsigned int*)sXH)[i]  = 0u;
        ((unsigned int*)sH1H)[i] = 0u;
    }
    for (int i = tid; i < (int)(4*16*72/2); i += 512)
        ((unsigned int*)sH0H)[i] = 0u;
    __syncthreads();
    // stage x_0 into buffer 0
    if (tid < 96){
        const float4 v = *reinterpret_cast<const float4*>(&x[(size_t)r0 * 24 + tid * 4]);
        const int row = (tid * 4) / 24, col = (tid * 4) % 24;
        ushort4 w = { f2bf(v.x), f2bf(v.y), f2bf(v.z), f2bf(v.w) };
        *reinterpret_cast<ushort4*>(&sXH[0][row][col]) = w;
    }
    __syncthreads();

    if (half == 0){
        // ================= LAYER 0 waves (group 0) =================
        bf16x8 B0H[4][3];   // ks0 = Wih0 (K=24 pad 32), ks1,2 = Whh0; scaled bf16
        #pragma unroll
        for (int gt = 0; gt < 4; ++gt){
            const int c = gt * 64 + cg;
            const float sc = WS[gt];
            bf16x8 bh = {0,0,0,0,0,0,0,0};
            if (g < 3){
                const float* pw = &Wih0[c * 24 + g * 8];
                #pragma unroll
                for (int j = 0; j < 8; ++j) bh[j] = (short)f2bf(pw[j] * sc);
            }
            B0H[gt][0] = bh;
            #pragma unroll
            for (int ks = 0; ks < 2; ++ks){
                bf16x8 ch;
                const float* pw = &Whh0[c * 64 + ks * 32 + g * 8];
                #pragma unroll
                for (int j = 0; j < 8; ++j) ch[j] = (short)f2bf(pw[j] * sc);
                B0H[gt][1+ks] = ch;
            }
        }
        float b0[4];
        #pragma unroll
        for (int gt = 0; gt < 4; ++gt) b0[gt] = (bih0[gt*64 + cg] + bhh0[gt*64 + cg]) * WS[gt];

        const float* xfp = x + ((size_t)BATCH + r0) * 24 + tid * 4;  // x for tick t+1
        float c0[4] = {0,0,0,0};
        int ph = 0;
        int pw = 0, pr = 3;   // pw = t%4 (write h0_t), pr = (t-1)%4 (read h0_{t-1})
        for (int t = 0; t < SEQ; ++t){
            const int px = t & 1;
            const bool ldx = (tid < 96) && (t + 1 < SEQ);
            float4 pref;
            if (ldx){ pref = *reinterpret_cast<const float4*>(xfp); xfp += (size_t)BATCH * 24; }

            const bf16x8 AxH = ldfrag(&sXH[px][lr][g*8]);
            bf16x8 A0H[2];
            #pragma unroll
            for (int ks = 0; ks < 2; ++ks)
                A0H[ks] = ldfrag(&sH0H[pr][lr][ks*32 + g*8]);

            f32x4 a0[4];
            #pragma unroll
            for (int gt = 0; gt < 4; ++gt){ f32x4 a = {b0[gt],b0[gt],b0[gt],b0[gt]}; a0[gt] = a; }
            #pragma unroll
            for (int gt = 0; gt < 4; ++gt) a0[gt] = MFMA(AxH, B0H[gt][0], a0[gt]);
            #pragma unroll
            for (int ks = 0; ks < 2; ++ks){
                #pragma unroll
                for (int gt = 0; gt < 4; ++gt) a0[gt] = MFMA(A0H[ks], B0H[gt][1+ks], a0[gt]);
            }
            unsigned short hh[4];
            #pragma unroll
            for (int i = 0; i < 4; ++i)
                hh[i] = f2bf(cellupd(a0[0][i], a0[1][i], a0[2][i], a0[3][i], c0[i]));
            // x-stage write BEFORE the cross-group wait (group-private buffer)
            if (ldx){
                const int row = (tid * 4) / 24, col = (tid * 4) % 24;
                ushort4 w = { f2bf(pref.x), f2bf(pref.y), f2bf(pref.z), f2bf(pref.w) };
                *reinterpret_cast<ushort4*>(&sXH[px ^ 1][row][col]) = w;
            }
            // overwrite guard: buffer pw holds h0_{t-4}, consumed by l1 at tick t-3
            if (t >= 4) wait_ge(&sync[5], t - 3);
            #pragma unroll
            for (int i = 0; i < 4; ++i)
                sH0H[pw][g * 4 + i][cg] = hh[i];
            gbar(&sync[0], &sync[2], &sync[4], t, ph, l);
            pr = pw;
            pw = (pw + 1) & 3;
        }
    } else {
        // ================= LAYER 1 + head waves (group 1) =================
        bf16x8 B1H[4][4];   // ks0,1 = Wih1 (h0 in), ks2,3 = Whh1 (h1 fb); scaled
        #pragma unroll
        for (int gt = 0; gt < 4; ++gt){
            const int c = gt * 64 + cg;
            const float sc = WS[gt];
            #pragma unroll
            for (int ks = 0; ks < 2; ++ks){
                bf16x8 ch;
                const float* pw = &Wih1[c * 64 + ks * 32 + g * 8];
                #pragma unroll
                for (int j = 0; j < 8; ++j) ch[j] = (short)f2bf(pw[j] * sc);
                B1H[gt][ks] = ch;
            }
            #pragma unroll
            for (int ks = 0; ks < 2; ++ks){
                bf16x8 ch;
                const float* pw = &Whh1[c * 64 + ks * 32 + g * 8];
                #pragma unroll
                for (int j = 0; j < 8; ++j) ch[j] = (short)f2bf(pw[j] * sc);
                B1H[gt][2+ks] = ch;
            }
        }
        float b1[4];
        #pragma unroll
        for (int gt = 0; gt < 4; ++gt) b1[gt] = (bih1[gt*64 + cg] + bhh1[gt*64 + cg]) * WS[gt];

        // head weights: keep hi+lo, UNSCALED
        const int oc = lr;
        bf16x8 WoH[2], WoL[2];
        #pragma unroll
        for (int tt = 0; tt < 2; ++tt){
            bf16x8 bh = {0,0,0,0,0,0,0,0}, bl = {0,0,0,0,0,0,0,0};
            if (oc < NOUT){
                const float* pw = &Wout[oc * 64 + tt * 32 + g * 8];
                #pragma unroll
                for (int j = 0; j < 8; ++j){ unsigned short hh, ll; splitf(pw[j], hh, ll); bh[j]=(short)hh; bl[j]=(short)ll; }
            }
            WoH[tt] = bh; WoL[tt] = bl;
        }
        const float bo0 = (oc < NOUT) ? bout[oc] : 0.f;
        float* houtp = out + (size_t)(r0 + g * 4) * NOUT + oc;

        float c1[4] = {0,0,0,0};
        int ph = 0;
        int pr0 = 0;   // (t-1) % 4, starting at t=1
        for (int t = 1; t <= SEQ; ++t){
            const int p = t & 1;
            // own-group feedback frags (= h1_{t-2}, also the head's input)
            bf16x8 A1H[2];
            #pragma unroll
            for (int ks = 0; ks < 2; ++ks)
                A1H[ks] = ldfrag(&sH1H[p][lr][ks*32 + g*8]);
            // h0_{t-1} ready? (l0 runs ahead -> almost always satisfied)
            wait_ge(&sync[4], t - 1);
            bf16x8 A0H[2];
            #pragma unroll
            for (int ks = 0; ks < 2; ++ks)
                A0H[ks] = ldfrag(&sH0H[pr0][lr][ks*32 + g*8]);

            f32x4 a1[4];
            #pragma unroll
            for (int gt = 0; gt < 4; ++gt){ f32x4 a = {b1[gt],b1[gt],b1[gt],b1[gt]}; a1[gt] = a; }
            // feedback MFMAs first (A0 read latency hides underneath)
            #pragma unroll
            for (int ks = 0; ks < 2; ++ks){
                #pragma unroll
                for (int gt = 0; gt < 4; ++gt) a1[gt] = MFMA(A1H[ks], B1H[gt][2+ks], a1[gt]);
            }
            // head for step t-2: rotating wave, reuses A1H (no LDS reads, no waits)
            if (t >= 2 && w2 == (t & 3)){
                f32x4 ha = {bo0, bo0, bo0, bo0};
                ha = MFMA(A1H[0], WoH[0], ha);
                ha = MFMA(A1H[0], WoL[0], ha);
                ha = MFMA(A1H[1], WoH[1], ha);
                ha = MFMA(A1H[1], WoL[1], ha);
                if (oc < NOUT){
                    #pragma unroll
                    for (int i = 0; i < 4; ++i)
                        houtp[(size_t)i * NOUT] = ha[i];
                }
            }
            if (t >= 2) houtp += (size_t)BATCH * NOUT;
            // input-side MFMAs
            #pragma unroll
            for (int ks = 0; ks < 2; ++ks){
                #pragma unroll
                for (int gt = 0; gt < 4; ++gt) a1[gt] = MFMA(A0H[ks], B1H[gt][ks], a1[gt]);
            }
            #pragma unroll
            for (int i = 0; i < 4; ++i)
                sH1H[p ^ 1][g * 4 + i][cg] =
                    f2bf(cellupd(a1[0][i], a1[1][i], a1[2][i], a1[3][i], c1[i]));
            gbar(&sync[1], &sync[3], &sync[5], t, ph, l);
            pr0 = (pr0 + 1) & 3;
        }
        // epilogue: head for step SEQ-1 (h1_{SEQ-1} in sH1[(SEQ+1)&1], stable)
        {
            const int pe = (SEQ + 1) & 1;
            if (w2 == ((SEQ + 1) & 3)){
                bf16x8 A1H0 = ldfrag(&sH1H[pe][lr][g*8]);
                bf16x8 A1H1 = ldfrag(&sH1H[pe][lr][32 + g*8]);
                f32x4 ha = {bo0, bo0, bo0, bo0};
                ha = MFMA(A1H0, WoH[0], ha);
                ha = MFMA(A1H0, WoL[0], ha);
                ha = MFMA(A1H1, WoH[1], ha);
                ha = MFMA(A1H1, WoL[1], ha);
                if (oc < NOUT){
                    #pragma unroll
                    for (int i = 0; i < 4; ++i)
                        houtp[(size_t)i * NOUT] = ha[i];
                }
            }
        }
    }
}

extern "C" void kernel_launch(void* const* d_in, const int* in_sizes, int n_in,
                              void* d_out, int out_size, void* d_ws, size_t ws_size,
                              hipStream_t stream)
{
    const float* x    = (const float*)d_in[0];
    const float* Wih0 = (const float*)d_in[1];
    const float* Whh0 = (const float*)d_in[2];
    const float* bih0 = (const float*)d_in[3];
    const float* bhh0 = (const float*)d_in[4];
    const float* Wih1 = (const float*)d_in[5];
    const float* Whh1 = (const float*)d_in[6];
    const float* bih1 = (const float*)d_in[7];
    const float* bhh1 = (const float*)d_in[8];
    const float* Wout = (const float*)d_in[9];
    const float* bout = (const float*)d_in[10];
    float* out = (float*)d_out;

    lstm_fused<<<NBLK, 512, 0, stream>>>(x, Wih0, Whh0, bih0, bhh0,
                                         Wih1, Whh1, bih1, bhh1,
                                         Wout, bout, out);
}

// Round 21
// 165.565 us; speedup vs baseline: 1.0776x; 1.0615x over previous
//
#include <hip/hip_runtime.h>
#include <hip/hip_bf16.h>
#include <math.h>

#define SEQ   168
#define BATCH 4096
#define NOUT  9
#define NBLK  256        // BATCH / 16

typedef short bf16x8 __attribute__((ext_vector_type(8)));
typedef float f32x4  __attribute__((ext_vector_type(4)));

#define MFMA(a,b,c) __builtin_amdgcn_mfma_f32_16x16x32_bf16((a),(b),(c),0,0,0)

static __device__ __forceinline__ float bf2f(unsigned short h){
    unsigned int u = ((unsigned int)h) << 16;
    return __builtin_bit_cast(float, u);
}
static __device__ __forceinline__ unsigned short f2bf(float f){  // HW RNE
    return __builtin_bit_cast(unsigned short, __float2bfloat16(f));
}
// 2-term split kept ONLY for the head weights (4 MFMAs, direct output impact)
static __device__ __forceinline__ void splitf(float f, unsigned short& hi, unsigned short& lo){
    hi = f2bf(f);
    float r = f - bf2f(hi);
    lo = (unsigned short)(__builtin_bit_cast(unsigned int, r) >> 16);
}
static __device__ __forceinline__ float sigf(float x){
    return __builtin_amdgcn_rcpf(1.0f + __expf(-x));
}
static __device__ __forceinline__ float tanhf_(float x){
    float r = __builtin_amdgcn_rcpf(1.0f + __expf(2.0f * x));
    return fmaf(-2.0f, r, 1.0f);
}
static __device__ __forceinline__ bf16x8 ldfrag(const unsigned short* p){
    const uint4 q = *reinterpret_cast<const uint4*>(p);
    return __builtin_bit_cast(bf16x8, q);
}

// group-local sense-reversing barrier over 4 waves; last arriver posts `tickval`
static __device__ __forceinline__ void gbar(int* cnt, int* phs, int* done,
                                            int tickval, int& ph, int lane){
    asm volatile("s_waitcnt lgkmcnt(0)" ::: "memory");
    if (lane == 0){
        int old = __hip_atomic_fetch_add(cnt, 1, __ATOMIC_ACQ_REL,
                                         __HIP_MEMORY_SCOPE_WORKGROUP);
        if (old == 3){
            *cnt = 0;
            __hip_atomic_store(done, tickval, __ATOMIC_RELEASE,
                               __HIP_MEMORY_SCOPE_WORKGROUP);
            __hip_atomic_store(phs, ph ^ 1, __ATOMIC_RELEASE,
                               __HIP_MEMORY_SCOPE_WORKGROUP);
        }
    }
    while (__hip_atomic_load(phs, __ATOMIC_ACQUIRE,
                             __HIP_MEMORY_SCOPE_WORKGROUP) == ph)
        __builtin_amdgcn_s_sleep(1);
    ph ^= 1;
}
static __device__ __forceinline__ void wait_ge(int* done, int need){
    if (__hip_atomic_load(done, __ATOMIC_ACQUIRE, __HIP_MEMORY_SCOPE_WORKGROUP) >= need) return;
    do { __builtin_amdgcn_s_sleep(1); }
    while (__hip_atomic_load(done, __ATOMIC_ACQUIRE, __HIP_MEMORY_SCOPE_WORKGROUP) < need);
}

// r13 exact (empirical best, 166.9 us): r10 schedule, 1-term bf16 gate weights.
//   Group 0 (waves 0-3): layer0 tick t in [0,SEQ): h0_t -> sH0[t%3].
//   Group 1 (waves 4-7): layer1 tick t in [1,SEQ]: step t-1 + head for step t-2
//     on a rotating wave reusing the live A1H frags; epilogue emits step SEQ-1.
// h0 triple-buffered: l0 overwrite-guard l1_done >= t-2; l1 read-guard
// l0_done >= t-1 -> groups decouple with ~1 tick of slack each way.
__global__ __launch_bounds__(512, 2)
void lstm_fused(const float* __restrict__ x,
                const float* __restrict__ Wih0, const float* __restrict__ Whh0,
                const float* __restrict__ bih0, const float* __restrict__ bhh0,
                const float* __restrict__ Wih1, const float* __restrict__ Whh1,
                const float* __restrict__ bih1, const float* __restrict__ bhh1,
                const float* __restrict__ Wout, const float* __restrict__ bout,
                float* __restrict__ out)
{
    __shared__ __align__(16) unsigned short sXH[2][16][72];   // x hi, stride 144B
    __shared__ __align__(16) unsigned short sH0H[3][16][72];  // h0 hi, triple buf
    __shared__ __align__(16) unsigned short sH1H[2][16][72];  // h1 hi
    __shared__ int sync[8];  // [0,1]=cnt, [2,3]=phase, [4]=l0_done, [5]=l1_done

    const int tid  = threadIdx.x;
    const int half = tid >> 8;
    const int w2   = (tid >> 6) & 3;
    const int l    = tid & 63;
    const int lr   = l & 15;
    const int g    = l >> 4;
    const int r0   = blockIdx.x * 16;
    const int cg   = w2 * 16 + lr;

    if (tid < 8) sync[tid] = (tid == 4) ? -1 : 0;

    for (int i = tid; i < (int)(2*16*72/2); i += 512){
        ((unsigned int*)sXH)[i]  = 0u;
        ((unsigned int*)sH1H)[i] = 0u;
    }
    for (int i = tid; i < (int)(3*16*72/2); i += 512)
        ((unsigned int*)sH0H)[i] = 0u;
    __syncthreads();
    // stage x_0 into buffer 0
    if (tid < 96){
        const float4 v = *reinterpret_cast<const float4*>(&x[(size_t)r0 * 24 + tid * 4]);
        const int row = (tid * 4) / 24, col = (tid * 4) % 24;
        ushort4 w = { f2bf(v.x), f2bf(v.y), f2bf(v.z), f2bf(v.w) };
        *reinterpret_cast<ushort4*>(&sXH[0][row][col]) = w;
    }
    __syncthreads();

    if (half == 0){
        // ================= LAYER 0 waves (group 0) =================
        bf16x8 B0H[4][3];   // ks0 = Wih0 (K=24 pad 32), ks1,2 = Whh0; 1-term bf16
        #pragma unroll
        for (int gt = 0; gt < 4; ++gt){
            const int c = gt * 64 + cg;
            bf16x8 bh = {0,0,0,0,0,0,0,0};
            if (g < 3){
                const float* pw = &Wih0[c * 24 + g * 8];
                #pragma unroll
                for (int j = 0; j < 8; ++j) bh[j] = (short)f2bf(pw[j]);
            }
            B0H[gt][0] = bh;
            #pragma unroll
            for (int ks = 0; ks < 2; ++ks){
                bf16x8 ch;
                const float* pw = &Whh0[c * 64 + ks * 32 + g * 8];
                #pragma unroll
                for (int j = 0; j < 8; ++j) ch[j] = (short)f2bf(pw[j]);
                B0H[gt][1+ks] = ch;
            }
        }
        float b0[4];
        #pragma unroll
        for (int gt = 0; gt < 4; ++gt) b0[gt] = bih0[gt*64 + cg] + bhh0[gt*64 + cg];

        const float* xfp = x + ((size_t)BATCH + r0) * 24 + tid * 4;  // x for tick t+1
        float c0[4] = {0,0,0,0};
        int ph = 0;
        int pw = 0, pr = 2;   // pw = t%3 (write h0_t), pr = (t-1)%3 (read h0_{t-1})
        for (int t = 0; t < SEQ; ++t){
            const int px = t & 1;
            const bool ldx = (tid < 96) && (t + 1 < SEQ);
            float4 pref;
            if (ldx){ pref = *reinterpret_cast<const float4*>(xfp); xfp += (size_t)BATCH * 24; }

            const bf16x8 AxH = ldfrag(&sXH[px][lr][g*8]);
            bf16x8 A0H[2];
            #pragma unroll
            for (int ks = 0; ks < 2; ++ks)
                A0H[ks] = ldfrag(&sH0H[pr][lr][ks*32 + g*8]);

            f32x4 a0[4];
            #pragma unroll
            for (int gt = 0; gt < 4; ++gt){ f32x4 a = {b0[gt],b0[gt],b0[gt],b0[gt]}; a0[gt] = a; }
            #pragma unroll
            for (int gt = 0; gt < 4; ++gt) a0[gt] = MFMA(AxH, B0H[gt][0], a0[gt]);
            #pragma unroll
            for (int ks = 0; ks < 2; ++ks){
                #pragma unroll
                for (int gt = 0; gt < 4; ++gt) a0[gt] = MFMA(A0H[ks], B0H[gt][1+ks], a0[gt]);
            }
            unsigned short hh[4];
            #pragma unroll
            for (int i = 0; i < 4; ++i){
                const float ig = sigf(a0[0][i]);
                const float fg = sigf(a0[1][i]);
                const float gg = tanhf_(a0[2][i]);
                const float og = sigf(a0[3][i]);
                c0[i] = fg * c0[i] + ig * gg;
                hh[i] = f2bf(og * tanhf_(c0[i]));
            }
            // overwrite guard: buffer pw holds h0_{t-3}, consumed by l1 at tick t-2
            if (t >= 3) wait_ge(&sync[5], t - 2);
            #pragma unroll
            for (int i = 0; i < 4; ++i)
                sH0H[pw][g * 4 + i][cg] = hh[i];
            if (ldx){
                const int row = (tid * 4) / 24, col = (tid * 4) % 24;
                ushort4 w = { f2bf(pref.x), f2bf(pref.y), f2bf(pref.z), f2bf(pref.w) };
                *reinterpret_cast<ushort4*>(&sXH[px ^ 1][row][col]) = w;
            }
            gbar(&sync[0], &sync[2], &sync[4], t, ph, l);
            pr = pw;
            pw = (pw == 2) ? 0 : pw + 1;
        }
    } else {
        // ================= LAYER 1 + head waves (group 1) =================
        bf16x8 B1H[4][4];   // ks0,1 = Wih1 (h0 in), ks2,3 = Whh1 (h1 fb); 1-term
        #pragma unroll
        for (int gt = 0; gt < 4; ++gt){
            const int c = gt * 64 + cg;
            #pragma unroll
            for (int ks = 0; ks < 2; ++ks){
                bf16x8 ch;
                const float* pw = &Wih1[c * 64 + ks * 32 + g * 8];
                #pragma unroll
                for (int j = 0; j < 8; ++j) ch[j] = (short)f2bf(pw[j]);
                B1H[gt][ks] = ch;
            }
            #pragma unroll
            for (int ks = 0; ks < 2; ++ks){
                bf16x8 ch;
                const float* pw = &Whh1[c * 64 + ks * 32 + g * 8];
                #pragma unroll
                for (int j = 0; j < 8; ++j) ch[j] = (short)f2bf(pw[j]);
                B1H[gt][2+ks] = ch;
            }
        }
        float b1[4];
        #pragma unroll
        for (int gt = 0; gt < 4; ++gt) b1[gt] = bih1[gt*64 + cg] + bhh1[gt*64 + cg];

        // head weights: keep hi+lo (4 MFMAs total, direct output impact)
        const int oc = lr;
        bf16x8 WoH[2], WoL[2];
        #pragma unroll
        for (int tt = 0; tt < 2; ++tt){
            bf16x8 bh = {0,0,0,0,0,0,0,0}, bl = {0,0,0,0,0,0,0,0};
            if (oc < NOUT){
                const float* pw = &Wout[oc * 64 + tt * 32 + g * 8];
                #pragma unroll
                for (int j = 0; j < 8; ++j){ unsigned short hh, ll; splitf(pw[j], hh, ll); bh[j]=(short)hh; bl[j]=(short)ll; }
            }
            WoH[tt] = bh; WoL[tt] = bl;
        }
        const float bo0 = (oc < NOUT) ? bout[oc] : 0.f;
        float* houtp = out + (size_t)(r0 + g * 4) * NOUT + oc;

        float c1[4] = {0,0,0,0};
        int ph = 0;
        int pr0 = 0;   // (t-1) % 3, starting at t=1
        for (int t = 1; t <= SEQ; ++t){
            const int p = t & 1;
            // own-group feedback frags (= h1_{t-2}, also the head's input)
            bf16x8 A1H[2];
            #pragma unroll
            for (int ks = 0; ks < 2; ++ks)
                A1H[ks] = ldfrag(&sH1H[p][lr][ks*32 + g*8]);
            // h0_{t-1} ready? (l0 runs ahead -> almost always satisfied)
            wait_ge(&sync[4], t - 1);
            bf16x8 A0H[2];
            #pragma unroll
            for (int ks = 0; ks < 2; ++ks)
                A0H[ks] = ldfrag(&sH0H[pr0][lr][ks*32 + g*8]);

            f32x4 a1[4];
            #pragma unroll
            for (int gt = 0; gt < 4; ++gt){ f32x4 a = {b1[gt],b1[gt],b1[gt],b1[gt]}; a1[gt] = a; }
            // feedback MFMAs first (A0 read latency hides underneath)
            #pragma unroll
            for (int ks = 0; ks < 2; ++ks){
                #pragma unroll
                for (int gt = 0; gt < 4; ++gt) a1[gt] = MFMA(A1H[ks], B1H[gt][2+ks], a1[gt]);
            }
            // head for step t-2: rotating wave, reuses A1H (no LDS reads, no waits)
            if (t >= 2 && w2 == (t & 3)){
                f32x4 ha = {bo0, bo0, bo0, bo0};
                ha = MFMA(A1H[0], WoH[0], ha);
                ha = MFMA(A1H[0], WoL[0], ha);
                ha = MFMA(A1H[1], WoH[1], ha);
                ha = MFMA(A1H[1], WoL[1], ha);
                if (oc < NOUT){
                    #pragma unroll
                    for (int i = 0; i < 4; ++i)
                        houtp[(size_t)i * NOUT] = ha[i];
                }
            }
            if (t >= 2) houtp += (size_t)BATCH * NOUT;
            // input-side MFMAs
            #pragma unroll
            for (int ks = 0; ks < 2; ++ks){
                #pragma unroll
                for (int gt = 0; gt < 4; ++gt) a1[gt] = MFMA(A0H[ks], B1H[gt][ks], a1[gt]);
            }
            #pragma unroll
            for (int i = 0; i < 4; ++i){
                const float ig = sigf(a1[0][i]);
                const float fg = sigf(a1[1][i]);
                const float gg = tanhf_(a1[2][i]);
                const float og = sigf(a1[3][i]);
                c1[i] = fg * c1[i] + ig * gg;
                sH1H[p ^ 1][g * 4 + i][cg] = f2bf(og * tanhf_(c1[i]));
            }
            gbar(&sync[1], &sync[3], &sync[5], t, ph, l);
            pr0 = (pr0 == 2) ? 0 : pr0 + 1;
        }
        // epilogue: head for step SEQ-1 (h1_{SEQ-1} in sH1[(SEQ+1)&1], stable)
        {
            const int pe = (SEQ + 1) & 1;
            if (w2 == ((SEQ + 1) & 3)){
                bf16x8 A1H0 = ldfrag(&sH1H[pe][lr][g*8]);
                bf16x8 A1H1 = ldfrag(&sH1H[pe][lr][32 + g*8]);
                f32x4 ha = {bo0, bo0, bo0, bo0};
                ha = MFMA(A1H0, WoH[0], ha);
                ha = MFMA(A1H0, WoL[0], ha);
                ha = MFMA(A1H1, WoH[1], ha);
                ha = MFMA(A1H1, WoL[1], ha);
                if (oc < NOUT){
                    #pragma unroll
                    for (int i = 0; i < 4; ++i)
                        houtp[(size_t)i * NOUT] = ha[i];
                }
            }
        }
    }
}

extern "C" void kernel_launch(void* const* d_in, const int* in_sizes, int n_in,
                              void* d_out, int out_size, void* d_ws, size_t ws_size,
                              hipStream_t stream)
{
    const float* x    = (const float*)d_in[0];
    const float* Wih0 = (const float*)d_in[1];
    const float* Whh0 = (const float*)d_in[2];
    const float* bih0 = (const float*)d_in[3];
    const float* bhh0 = (const float*)d_in[4];
    const float* Wih1 = (const float*)d_in[5];
    const float* Whh1 = (const float*)d_in[6];
    const float* bih1 = (const float*)d_in[7];
    const float* bhh1 = (const float*)d_in[8];
    const float* Wout = (const float*)d_in[9];
    const float* bout = (const float*)d_in[10];
    float* out = (float*)d_out;

    lstm_fused<<<NBLK, 512, 0, stream>>>(x, Wih0, Whh0, bih0, bhh0,
                                         Wih1, Whh1, bih1, bhh1,
                                         Wout, bout, out);
}